// Round 4
// baseline (945.372 us; speedup 1.0000x reference)
//
#include <hip/hip_runtime.h>
#include <stdint.h>
#include <math.h>

// ---------------------------------------------------------------------------
// DecoderRNN: 2-layer LSTM (B=32, T=64, E=H=512) + vocab projection (V=50257)
//
//   K1  build_inputs : gather embeddings + features -> inputs_bf [65][32][512]
//   K2  cast weights to bf16, pad-cast w_out
//   K3  lstm_pipeline: persistent kernel, 64 WGs (32/layer). Weights live in
//       LDS (128 KB/WG, XOR-swizzled) -> deterministic residency, no VGPR
//       gamble. h exchanged via coherent point (sc0 sc1). Sync: per-WG slot
//       words on private 64B lines, plain relaxed stores + 32-lane polls --
//       zero atomic RMW. Layer 0 free-runs; layer 1 chases.
//   K4  logits_gemm  : 128x128x32 bf16 MFMA GEMM (m97 structure), f32 + bias.
// ---------------------------------------------------------------------------

typedef unsigned short u16;
typedef __bf16 bf16x8 __attribute__((ext_vector_type(8)));
typedef float  f32x4  __attribute__((ext_vector_type(4)));

#define BATCH   32
#define SEQT    64
#define NSTEP   65            // T+1 timesteps
#define EMB     512
#define HID     512
#define VOCAB   50257
#define VPAD    50304         // 393*128
#define NWG_LSTM 64

// dynamic LDS layout (bytes)
#define LDS_WTS     0         // 4 waves x (ih 16KB + hh 16KB) = 131072
#define LDS_GATES   131072    // float[4][32][16] = 8192
#define LDS_C       139264    // float[32][16]    = 2048
#define LDS_BIAS    141312    // float[4][16]     = 256
#define LDS_TOTAL   141568

static __device__ __forceinline__ u16 f2bf(float f) {
  unsigned u = __float_as_uint(f);
  u += 0x7FFFu + ((u >> 16) & 1u);
  return (u16)(u >> 16);
}

static __device__ __forceinline__ bf16x8 ld_frag(const u16* p16) {
  union { uint4 u; bf16x8 v; } f;
  f.u = *(const uint4*)p16;
  return f.v;
}

// Coherent-point (bypass L1+L2) 16B load. Caller MUST do
// s_waitcnt vmcnt(0) + sched_barrier(0) before using the result.
static __device__ __forceinline__ bf16x8 ld_frag_sys(const u16* p16) {
  union { uint4 u; bf16x8 v; } f;
  asm volatile("global_load_dwordx4 %0, %1, off sc0 sc1"
               : "=v"(f.u) : "v"(p16));
  return f.v;
}

// Coherent-point 8B store (write-through past non-coherent L2).
static __device__ __forceinline__ void st_sys64(u16* p, unsigned long long v) {
  asm volatile("global_store_dwordx2 %0, %1, off sc0 sc1"
               :: "v"(p), "v"(v) : "memory");
}

static __device__ __forceinline__ float sigmoid_fast(float x) {
  return 1.0f / (1.0f + __expf(-x));
}
static __device__ __forceinline__ float tanh_fast(float x) {
  return 1.0f - 2.0f / (__expf(2.0f * x) + 1.0f);
}

// 32-lane slot poll: lane reads slots[base + (lane&31)*16]; exit when all>=tgt.
// Call from wave 0 (tid<64) only, then __syncthreads().
static __device__ __forceinline__ void poll_slots(const unsigned* slots,
                                                  int base_slot, unsigned tgt,
                                                  int lane) {
  const unsigned* p = slots + (base_slot + (lane & 31)) * 16;
  for (;;) {
    unsigned v = __hip_atomic_load(p, __ATOMIC_RELAXED, __HIP_MEMORY_SCOPE_AGENT);
    if (__all((int)(v >= tgt))) break;
    __builtin_amdgcn_s_sleep(1);
  }
}

// ---------------------------------------------------------------------------
// K1
// ---------------------------------------------------------------------------
__global__ void build_inputs(const float* __restrict__ features,
                             const int*   __restrict__ captions,
                             const float* __restrict__ embed_w,
                             u16* __restrict__ dst) {
  int idx = blockIdx.x * blockDim.x + threadIdx.x;
  const int n = NSTEP * BATCH * EMB;
  if (idx >= n) return;
  int e = idx & (EMB - 1);
  int rem = idx >> 9;
  int b = rem & (BATCH - 1);
  int t = rem >> 5;
  float v;
  if (t == 0) v = features[b * EMB + e];
  else        v = embed_w[(size_t)captions[b * SEQT + (t - 1)] * EMB + e];
  dst[idx] = f2bf(v);
}

// ---------------------------------------------------------------------------
// K2
// ---------------------------------------------------------------------------
__global__ void cast_bf16(const float* __restrict__ src, u16* __restrict__ dst, int n4) {
  int i = blockIdx.x * blockDim.x + threadIdx.x;
  if (i >= n4) return;
  float4 v = ((const float4*)src)[i];
  ushort4 o;
  o.x = f2bf(v.x); o.y = f2bf(v.y); o.z = f2bf(v.z); o.w = f2bf(v.w);
  ((ushort4*)dst)[i] = o;
}

__global__ void cast_pad_wout(const float* __restrict__ src, u16* __restrict__ dst) {
  int i = blockIdx.x * blockDim.x + threadIdx.x;
  const int n4 = VPAD * 512 / 4;
  const int nsrc4 = VOCAB * 512 / 4;
  if (i >= n4) return;
  ushort4 o;
  if (i < nsrc4) {
    float4 v = ((const float4*)src)[i];
    o.x = f2bf(v.x); o.y = f2bf(v.y); o.z = f2bf(v.z); o.w = f2bf(v.w);
  } else {
    o.x = 0; o.y = 0; o.z = 0; o.w = 0;
  }
  ((ushort4*)dst)[i] = o;
}

// ---------------------------------------------------------------------------
// K3: persistent pipelined 2-layer LSTM. Weights in LDS, slot-signal sync.
// ---------------------------------------------------------------------------
__global__ __launch_bounds__(256, 1)
void lstm_pipeline(const u16* __restrict__ inputs_bf,   // [65][32][512]
                   const u16* __restrict__ wih0, const u16* __restrict__ whh0,
                   const float* __restrict__ b0,
                   const u16* __restrict__ wih1, const u16* __restrict__ whh1,
                   const float* __restrict__ b1,
                   u16* h0_all,                  // [65][32][512]
                   u16* h1_all,                  // [65][32][512]
                   u16* __restrict__ A_bf,       // [2048][512] rows (b*64+t)
                   unsigned* slots) {            // [64] x 16 u32 (64B stride)
  const int wg    = blockIdx.x;
  const int layer = wg >> 5;
  const int j0    = (wg & 31) * 16;
  const int tid   = threadIdx.x;
  const int lane  = tid & 63;
  const int wv    = tid >> 6;       // wave index == gate index
  const int l15   = lane & 15;
  const int lg    = lane >> 4;

  const u16*   wih  = layer ? wih1 : wih0;
  const u16*   whh  = layer ? whh1 : whh0;
  const float* bias = layer ? b1 : b0;
  const u16* xsrc  = layer ? h0_all : inputs_bf;   // same [t][b][512] layout
  const u16* hsrc  = layer ? h1_all : h0_all;
  u16*       hdst  = layer ? h1_all : h0_all;
  const int  own_base = layer ? 32 : 0;            // own layer's slot base

  extern __shared__ char smem[];
  float* gates_l = (float*)(smem + LDS_GATES);   // [g][b][jj] = [g*512+b*16+jj]
  float* c_l     = (float*)(smem + LDS_C);       // [b*16+jj]
  float* bias_l  = (float*)(smem + LDS_BIAS);    // [g*16+jj]

  for (int i = tid; i < BATCH * 16; i += 256) c_l[i] = 0.0f;
  if (tid < 64) bias_l[tid] = bias[(tid >> 4) * HID + j0 + (tid & 15)];

  // ---- stage this wave's weight slices into LDS (swizzled), one-time ----
  // wave block: rows wv*512+j0 .. +15 of W (16 rows x 512 k, 16 KB/matrix)
  // byte layout: row*1024 + ((k16*16) ^ ((row&7)<<4))
  {
    char* wbase = smem + wv * 32768;
    const u16* g0 = wih + (size_t)(wv * HID + j0) * 512;
    const u16* g1 = whh + (size_t)(wv * HID + j0) * 512;
#pragma unroll
    for (int m = 0; m < 2; ++m) {
      char* lbase = wbase + m * 16384;
      const u16* g = m ? g1 : g0;
#pragma unroll
      for (int c = 0; c < 16; ++c) {
        int q   = lane + 64 * c;     // 16B-chunk id, 1024 per matrix-block
        int row = q >> 6;            // 64 chunks per row
        int k16 = q & 63;
        uint4 v = *(const uint4*)(g + (size_t)row * 512 + k16 * 8);
        int boff = row * 1024 + ((k16 * 16) ^ ((row & 7) << 4));
        *(uint4*)(lbase + boff) = v;
      }
    }
  }
  __syncthreads();

  // per-lane constant pieces of the weight-fragment LDS address
  const char* wv_base = smem + wv * 32768;
  const int   rowbase = l15 * 1024;
  const int   swz     = (l15 & 7) << 4;
  const int   lgoff   = lg * 16;

  for (int t = 0; t < NSTEP; ++t) {
    // ---------------- X phase ----------------
    if (layer == 1) {                 // need h0[t]: all L0 slots >= t+1
      if (tid < 64) poll_slots(slots, 0, (unsigned)(t + 1), lane);
      __syncthreads();
    }
    f32x4 acc0 = {0.f, 0.f, 0.f, 0.f};
    f32x4 acc1 = {0.f, 0.f, 0.f, 0.f};
    {
      const u16* xr0 = xsrc + (size_t)t * (BATCH * HID) + (size_t)l15 * 512;
      const u16* xr1 = xr0 + 16 * 512;
      bf16x8 a0[16], a1[16];
      if (layer == 1) {
#pragma unroll
        for (int kk = 0; kk < 16; ++kk) {
          int k0 = kk * 32 + 8 * lg;
          a0[kk] = ld_frag_sys(xr0 + k0);
          a1[kk] = ld_frag_sys(xr1 + k0);
        }
      } else {
#pragma unroll
        for (int kk = 0; kk < 16; ++kk) {
          int k0 = kk * 32 + 8 * lg;
          a0[kk] = ld_frag(xr0 + k0);
          a1[kk] = ld_frag(xr1 + k0);
        }
      }
      asm volatile("s_waitcnt vmcnt(0)" ::: "memory");
      __builtin_amdgcn_sched_barrier(0);
#pragma unroll
      for (int kk = 0; kk < 16; ++kk) {
        union { uint4 u; bf16x8 v; } w;
        w.u = *(const uint4*)(wv_base + rowbase + ((kk * 64 + lgoff) ^ swz));
        acc0 = __builtin_amdgcn_mfma_f32_16x16x32_bf16(a0[kk], w.v, acc0, 0, 0, 0);
        acc1 = __builtin_amdgcn_mfma_f32_16x16x32_bf16(a1[kk], w.v, acc1, 0, 0, 0);
      }
    }
    // ---------------- H phase ----------------
    if (t > 0) {
      if (tid < 64) poll_slots(slots, own_base, (unsigned)t, lane);
      __syncthreads();
      const u16* hr0 = hsrc + (size_t)(t - 1) * (BATCH * HID) + (size_t)l15 * 512;
      const u16* hr1 = hr0 + 16 * 512;
      bf16x8 a0[16], a1[16];
#pragma unroll
      for (int kk = 0; kk < 16; ++kk) {
        int k0 = kk * 32 + 8 * lg;
        a0[kk] = ld_frag_sys(hr0 + k0);
        a1[kk] = ld_frag_sys(hr1 + k0);
      }
      asm volatile("s_waitcnt vmcnt(0)" ::: "memory");
      __builtin_amdgcn_sched_barrier(0);
#pragma unroll
      for (int kk = 0; kk < 16; ++kk) {
        union { uint4 u; bf16x8 v; } w;
        w.u = *(const uint4*)(wv_base + 16384 + rowbase + ((kk * 64 + lgoff) ^ swz));
        acc0 = __builtin_amdgcn_mfma_f32_16x16x32_bf16(a0[kk], w.v, acc0, 0, 0, 0);
        acc1 = __builtin_amdgcn_mfma_f32_16x16x32_bf16(a1[kk], w.v, acc1, 0, 0, 0);
      }
    }
    // C layout: col = lane&15, row = 4*(lane>>4)+reg
#pragma unroll
    for (int rr = 0; rr < 4; ++rr) {
      gates_l[wv * 512 + (4 * lg + rr) * 16 + l15]        = acc0[rr];
      gates_l[wv * 512 + (16 + 4 * lg + rr) * 16 + l15]   = acc1[rr];
    }
    __syncthreads();

    if (tid < 128) {
      const int b = tid >> 2;
      const int q = (tid & 3) * 4;
      float hv[4];
#pragma unroll
      for (int u = 0; u < 4; ++u) {
        const int jj = q + u;
        float gi = gates_l[0 * 512 + b * 16 + jj] + bias_l[0 * 16 + jj];
        float gf = gates_l[1 * 512 + b * 16 + jj] + bias_l[1 * 16 + jj];
        float gg = gates_l[2 * 512 + b * 16 + jj] + bias_l[2 * 16 + jj];
        float go = gates_l[3 * 512 + b * 16 + jj] + bias_l[3 * 16 + jj];
        float cp = c_l[b * 16 + jj];
        float cn = sigmoid_fast(gf) * cp + sigmoid_fast(gi) * tanh_fast(gg);
        c_l[b * 16 + jj] = cn;
        hv[u] = sigmoid_fast(go) * tanh_fast(cn);
      }
      union { ushort4 s; unsigned long long v; } pk;
      pk.s.x = f2bf(hv[0]); pk.s.y = f2bf(hv[1]);
      pk.s.z = f2bf(hv[2]); pk.s.w = f2bf(hv[3]);
      st_sys64(hdst + (size_t)t * (BATCH * HID) + b * HID + j0 + q, pk.v);
      if (layer == 1 && t >= 1)
        *(unsigned long long*)(A_bf + (size_t)(b * SEQT + (t - 1)) * HID + j0 + q) = pk.v;
    }
    // drain own stores to the coherent point, then signal own slot
    asm volatile("s_waitcnt vmcnt(0)" ::: "memory");
    __syncthreads();
    if (tid == 0)
      __hip_atomic_store(&slots[wg * 16], (unsigned)(t + 1),
                         __ATOMIC_RELAXED, __HIP_MEMORY_SCOPE_AGENT);
  }
}

// ---------------------------------------------------------------------------
// K4: logits GEMM (unchanged this round).
// ---------------------------------------------------------------------------
__global__ __launch_bounds__(256)
void logits_gemm(const u16* __restrict__ Ag,
                 const u16* __restrict__ Bg,
                 const float* __restrict__ b_out,
                 float* __restrict__ out) {
  const int mt = blockIdx.x;
  const int nt = blockIdx.y;
  const int m0 = mt * 128, v0 = nt * 128;
  const int tid  = threadIdx.x;
  const int lane = tid & 63;
  const int wv   = tid >> 6;
  const int l15  = lane & 15;
  const int lg   = lane >> 4;
  const int wm = (wv & 1) * 64;
  const int wn = (wv >> 1) * 64;

  __shared__ u16 As[128 * 32];
  __shared__ u16 Bs[128 * 32];

  f32x4 acc[4][4];
#pragma unroll
  for (int mi = 0; mi < 4; ++mi)
#pragma unroll
    for (int ni = 0; ni < 4; ++ni)
      acc[mi][ni] = (f32x4){0.f, 0.f, 0.f, 0.f};

  for (int kt = 0; kt < 16; ++kt) {
#pragma unroll
    for (int c = 0; c < 2; ++c) {
      int f16 = wv * 128 + c * 64 + lane;
      int row = f16 >> 2;
      int kc  = (f16 & 3) << 3;
      const u16* ga = Ag + (size_t)(m0 + row) * 512 + kt * 32 + kc;
      const u16* gb = Bg + (size_t)(v0 + row) * 512 + kt * 32 + kc;
      u16* la = &As[(wv * 128 + c * 64) * 8];
      u16* lb = &Bs[(wv * 128 + c * 64) * 8];
      __builtin_amdgcn_global_load_lds(
          (const __attribute__((address_space(1))) void*)ga,
          (__attribute__((address_space(3))) void*)la, 16, 0, 0);
      __builtin_amdgcn_global_load_lds(
          (const __attribute__((address_space(1))) void*)gb,
          (__attribute__((address_space(3))) void*)lb, 16, 0, 0);
    }
    asm volatile("s_waitcnt vmcnt(0)" ::: "memory");
    __syncthreads();

    bf16x8 af[4], bfr[4];
#pragma unroll
    for (int i = 0; i < 4; ++i) {
      af[i]  = ld_frag(&As[(wm + i * 16 + l15) * 32 + 8 * lg]);
      bfr[i] = ld_frag(&Bs[(wn + i * 16 + l15) * 32 + 8 * lg]);
    }
#pragma unroll
    for (int mi = 0; mi < 4; ++mi)
#pragma unroll
      for (int ni = 0; ni < 4; ++ni)
        acc[mi][ni] = __builtin_amdgcn_mfma_f32_16x16x32_bf16(af[mi], bfr[ni], acc[mi][ni], 0, 0, 0);
    __syncthreads();
  }

#pragma unroll
  for (int ni = 0; ni < 4; ++ni) {
    int v = v0 + wn + ni * 16 + l15;
    bool vok = (v < VOCAB);
    float bo = vok ? b_out[v] : 0.0f;
#pragma unroll
    for (int mi = 0; mi < 4; ++mi) {
      int mbase = m0 + wm + mi * 16 + 4 * lg;
#pragma unroll
      for (int rr = 0; rr < 4; ++rr) {
        if (vok) out[(size_t)(mbase + rr) * VOCAB + v] = acc[mi][ni][rr] + bo;
      }
    }
  }
}

// ---------------------------------------------------------------------------
// host
// ---------------------------------------------------------------------------
extern "C" void kernel_launch(void* const* d_in, const int* in_sizes, int n_in,
                              void* d_out, int out_size, void* d_ws, size_t ws_size,
                              hipStream_t stream) {
  const float* features = (const float*)d_in[0];
  const int*   captions = (const int*)d_in[1];
  const float* embed_w  = (const float*)d_in[2];
  const float* w_ih0    = (const float*)d_in[3];
  const float* w_hh0    = (const float*)d_in[4];
  const float* b0       = (const float*)d_in[5];
  const float* w_ih1    = (const float*)d_in[6];
  const float* w_hh1    = (const float*)d_in[7];
  const float* b1       = (const float*)d_in[8];
  const float* w_out    = (const float*)d_in[9];
  const float* b_out    = (const float*)d_in[10];
  float* out = (float*)d_out;

  char* ws = (char*)d_ws;
  size_t off = 0;
  auto alloc = [&](size_t bytes) -> void* {
    void* p = ws + off;
    off = (off + bytes + 255) & ~(size_t)255;
    return p;
  };
  unsigned* slots = (unsigned*)alloc(64 * 16 * sizeof(unsigned));  // 4 KB
  u16* inputs_bf = (u16*)alloc((size_t)NSTEP * BATCH * EMB * 2);
  u16* wih0_bf   = (u16*)alloc((size_t)4 * HID * EMB * 2);
  u16* whh0_bf   = (u16*)alloc((size_t)4 * HID * HID * 2);
  u16* wih1_bf   = (u16*)alloc((size_t)4 * HID * HID * 2);
  u16* whh1_bf   = (u16*)alloc((size_t)4 * HID * HID * 2);
  u16* wout_bf   = (u16*)alloc((size_t)VPAD * HID * 2);
  u16* h0_all    = (u16*)alloc((size_t)NSTEP * BATCH * HID * 2);
  u16* h1_all    = (u16*)alloc((size_t)NSTEP * BATCH * HID * 2);
  u16* A_bf      = (u16*)alloc((size_t)BATCH * SEQT * HID * 2);
  (void)ws_size; (void)in_sizes; (void)n_in; (void)out_size;

  // allow 141.5 KB dynamic LDS for the persistent LSTM kernel
  hipFuncSetAttribute((const void*)lstm_pipeline,
                      hipFuncAttributeMaxDynamicSharedMemorySize, LDS_TOTAL);

  hipMemsetAsync(slots, 0, 64 * 16 * sizeof(unsigned), stream);

  {
    int n = NSTEP * BATCH * EMB;
    build_inputs<<<(n + 255) / 256, 256, 0, stream>>>(features, captions, embed_w, inputs_bf);
  }
  {
    int n4 = 4 * HID * EMB / 4;
    cast_bf16<<<(n4 + 255) / 256, 256, 0, stream>>>(w_ih0, wih0_bf, n4);
    cast_bf16<<<(n4 + 255) / 256, 256, 0, stream>>>(w_hh0, whh0_bf, n4);
    cast_bf16<<<(n4 + 255) / 256, 256, 0, stream>>>(w_ih1, wih1_bf, n4);
    cast_bf16<<<(n4 + 255) / 256, 256, 0, stream>>>(w_hh1, whh1_bf, n4);
  }
  {
    int n4 = VPAD * 512 / 4;
    cast_pad_wout<<<(n4 + 255) / 256, 256, 0, stream>>>(w_out, wout_bf);
  }
  lstm_pipeline<<<NWG_LSTM, 256, LDS_TOTAL, stream>>>(
      inputs_bf, wih0_bf, whh0_bf, b0, wih1_bf, whh1_bf, b1,
      h0_all, h1_all, A_bf, slots);
  {
    dim3 grid(16, 393, 1);
    logits_gemm<<<grid, 256, 0, stream>>>(A_bf, wout_bf, b_out, out);
  }
}